// Round 11
// baseline (656.131 us; speedup 1.0000x reference)
//
#include <hip/hip_runtime.h>

// Problem constants (fixed by reference)
constexpr int B_ROWS = 65536;
constexpr int IN_F   = 1024;
constexpr int OUT_F  = 1024;

constexpr int BDIM = 512;            // 8 waves, 2M x 4N
constexpr int BM = 256, BN = 256, BK = 64;

typedef __bf16 bf16x8 __attribute__((ext_vector_type(8)));
typedef float  f32x4  __attribute__((ext_vector_type(4)));

__device__ __forceinline__ bf16x8 cvt8(f32x4 u0, f32x4 u1) {
    bf16x8 v;
    v[0] = (__bf16)u0[0]; v[1] = (__bf16)u0[1]; v[2] = (__bf16)u0[2]; v[3] = (__bf16)u0[3];
    v[4] = (__bf16)u1[0]; v[5] = (__bf16)u1[1]; v[6] = (__bf16)u1[2]; v[7] = (__bf16)u1[3];
    return v;
}

// async global->LDS, 16B per lane (wave stages 1KB contiguous at uniform lds base)
__device__ __forceinline__ void glds16(const __bf16* g, unsigned char* l) {
    __builtin_amdgcn_global_load_lds(
        (const __attribute__((address_space(1))) unsigned int*)(const void*)g,
        (__attribute__((address_space(3))) unsigned int*)(void*)l,
        16, 0, 0);
}

// ---------------- f32 -> bf16 convert: X (grid-strided, nt loads) + W ---------------
__global__ __launch_bounds__(256)
void cvt_all(const float* __restrict__ X, const float* __restrict__ W,
             __bf16* __restrict__ Xb, __bf16* __restrict__ Wb) {
    const int b = blockIdx.x;
    if (b < 2048) {   // X: 67.1M elems, 8 grid-strided chunks
        size_t i = ((size_t)b * 256 + threadIdx.x) * 16;
        #pragma unroll 1
        for (int it = 0; it < 8; ++it, i += (size_t)2048 * 256 * 16) {
            f32x4 a0 = __builtin_nontemporal_load((const f32x4*)(X + i));
            f32x4 a1 = __builtin_nontemporal_load((const f32x4*)(X + i + 4));
            f32x4 a2 = __builtin_nontemporal_load((const f32x4*)(X + i + 8));
            f32x4 a3 = __builtin_nontemporal_load((const f32x4*)(X + i + 12));
            *(bf16x8*)(Xb + i)     = cvt8(a0, a1);
            *(bf16x8*)(Xb + i + 8) = cvt8(a2, a3);
        }
    } else {          // W: 1M elems
        const size_t i = ((size_t)(b - 2048) * 256 + threadIdx.x) * 16;
        f32x4 a0 = __builtin_nontemporal_load((const f32x4*)(W + i));
        f32x4 a1 = __builtin_nontemporal_load((const f32x4*)(W + i + 4));
        f32x4 a2 = __builtin_nontemporal_load((const f32x4*)(W + i + 8));
        f32x4 a3 = __builtin_nontemporal_load((const f32x4*)(W + i + 12));
        *(bf16x8*)(Wb + i)     = cvt8(a0, a1);
        *(bf16x8*)(Wb + i + 8) = cvt8(a2, a3);
    }
}

// ---------------- 256x256, BK=64, 8-wave GEMM: A in LDS, B in REGISTERS --------------
// Mechanism change vs round-10 (which had MfmaUtil 27%, ~60% round-time stall on
// the 8-barrier lockstep): Wb (2MB) is L2/L3-resident, so B fragments are loaded
// DIRECTLY to registers (8 global_load_dwordx4/wave/round, issued 1 round ahead,
// bit-identical per-lane layout to the old LDS round-trip). B then needs no
// barrier protection -> ONE barrier + ONE counted vmcnt per round (was 8+4).
// A stays on the proven glds path: triple-buffered (3 x 32KB), staged 2 rounds
// ahead. Issue order per round t: B(t+1) x8, A(t+2) x4; end-of-round vmcnt(4)
// retires exactly {A(t+1), B(t+1)}, keeps A(t+2) in flight (no in-loop drain).
// LDS/round/CU: 160KB (was 256KB); B L2 traffic ~11 TB/s aggregate (cap 34.5).
__global__ __launch_bounds__(BDIM, 2)
void fused_linear_act(const __bf16* __restrict__ Xb,  // [B_ROWS][IN_F] bf16
                      const __bf16* __restrict__ Wb,  // [OUT_F][IN_F] bf16
                      const float* __restrict__ bias, // [OUT_F]
                      float* __restrict__ O)          // [B_ROWS][OUT_F]
{
    __shared__ __attribute__((aligned(16))) unsigned char lds[3 * 32768];  // 96 KB

    const int bx  = blockIdx.x;                 // 1024 blocks
    // XCD-aware: 4 consecutive blocks per XCD share one A panel (L2 reuse).
    const int xcd = bx & 7;
    const int idx = bx >> 3;
    const int nt  = idx & 3;
    const int mt  = xcd + 8 * (idx >> 2);
    const int m0 = mt * BM;
    const int n0 = nt * BN;

    const int tid  = threadIdx.x;
    const int lane = tid & 63;
    const int wave = tid >> 6;                  // 0..7, 2M x 4N
    const int wr2  = wave >> 2;
    const int w4   = wave & 3;
    const int lrow = lane & 15;
    const int quad = lane >> 4;

    // A staging source (per-lane, MFMA-order pre-swizzle; wave stages rows 32w..32w+31)
    const __bf16* agp = Xb + (size_t)(m0 + 32 * wave + lrow) * IN_F + quad * 8;
    // B register-load base (per-lane): row n0 + w4*64 + lrow, k-seg quad*8.
    // Fragment fn at +fn*16*IN_F, k-half at +32, K-tile t at +t*64.
    const __bf16* bgp = Wb + (size_t)(n0 + w4 * 64 + lrow) * IN_F + quad * 8;

    unsigned char* const b0 = lds;
    unsigned char* const b1 = lds + 32768;
    unsigned char* const b2 = lds + 65536;

    f32x4 acc[8][4];
    #pragma unroll
    for (int i = 0; i < 8; ++i)
        #pragma unroll
        for (int j = 0; j < 4; ++j)
            acc[i][j] = (f32x4){0.f, 0.f, 0.f, 0.f};

    bf16x8 aq0, aq1, aq2, aq3;
    bf16x8 bp0, bp1, bp2, bp3, bp4, bp5, bp6, bp7;   // B set even rounds
    bf16x8 bq0, bq1, bq2, bq3, bq4, bq5, bq6, bq7;   // B set odd rounds

// B(KT) -> register set PFX (8 global_load_dwordx4; frag fn x k-half)
#define BLOAD(PFX, KT) do { const __bf16* _b = bgp + (size_t)(KT) * 64; \
    PFX##0 = *(const bf16x8*)(_b);                PFX##1 = *(const bf16x8*)(_b + 16 * IN_F); \
    PFX##2 = *(const bf16x8*)(_b + 32 * IN_F);    PFX##3 = *(const bf16x8*)(_b + 48 * IN_F); \
    PFX##4 = *(const bf16x8*)(_b + 32);           PFX##5 = *(const bf16x8*)(_b + 32 + 16 * IN_F); \
    PFX##6 = *(const bf16x8*)(_b + 32 + 32 * IN_F); PFX##7 = *(const bf16x8*)(_b + 32 + 48 * IN_F); \
} while (0)
// A(KT) -> 32KB buffer STG (4 glds16/wave; kh0 at +0, kh1 at +16384)
#define GA4(STG, KT) do { unsigned char* _d = (STG) + wave * 2048; \
    const __bf16* _a = agp + (size_t)(KT) * 64; \
    glds16(_a, _d);            glds16(_a + 16 * IN_F, _d + 1024); \
    glds16(_a + 32, _d + 16384); glds16(_a + 32 + 16 * IN_F, _d + 16384 + 1024); } while (0)
// A fragments (4 ds_read_b128) for k-half KH, m-group MH from A buffer BUF
#define RA(BUF, KH, MH) do { \
    const unsigned char* _r = (BUF) + (KH) * 16384 + (wr2 * 8 + (MH) * 4) * 1024 + lane * 16; \
    aq0 = *(const bf16x8*)(_r);        aq1 = *(const bf16x8*)(_r + 1024); \
    aq2 = *(const bf16x8*)(_r + 2048); aq3 = *(const bf16x8*)(_r + 3072); } while (0)
#define MF16(MH, B0_, B1_, B2_, B3_) do { __builtin_amdgcn_s_setprio(1); \
    acc[(MH)*4+0][0] = __builtin_amdgcn_mfma_f32_16x16x32_bf16(aq0, B0_, acc[(MH)*4+0][0], 0, 0, 0); \
    acc[(MH)*4+0][1] = __builtin_amdgcn_mfma_f32_16x16x32_bf16(aq0, B1_, acc[(MH)*4+0][1], 0, 0, 0); \
    acc[(MH)*4+0][2] = __builtin_amdgcn_mfma_f32_16x16x32_bf16(aq0, B2_, acc[(MH)*4+0][2], 0, 0, 0); \
    acc[(MH)*4+0][3] = __builtin_amdgcn_mfma_f32_16x16x32_bf16(aq0, B3_, acc[(MH)*4+0][3], 0, 0, 0); \
    acc[(MH)*4+1][0] = __builtin_amdgcn_mfma_f32_16x16x32_bf16(aq1, B0_, acc[(MH)*4+1][0], 0, 0, 0); \
    acc[(MH)*4+1][1] = __builtin_amdgcn_mfma_f32_16x16x32_bf16(aq1, B1_, acc[(MH)*4+1][1], 0, 0, 0); \
    acc[(MH)*4+1][2] = __builtin_amdgcn_mfma_f32_16x16x32_bf16(aq1, B2_, acc[(MH)*4+1][2], 0, 0, 0); \
    acc[(MH)*4+1][3] = __builtin_amdgcn_mfma_f32_16x16x32_bf16(aq1, B3_, acc[(MH)*4+1][3], 0, 0, 0); \
    acc[(MH)*4+2][0] = __builtin_amdgcn_mfma_f32_16x16x32_bf16(aq2, B0_, acc[(MH)*4+2][0], 0, 0, 0); \
    acc[(MH)*4+2][1] = __builtin_amdgcn_mfma_f32_16x16x32_bf16(aq2, B1_, acc[(MH)*4+2][1], 0, 0, 0); \
    acc[(MH)*4+2][2] = __builtin_amdgcn_mfma_f32_16x16x32_bf16(aq2, B2_, acc[(MH)*4+2][2], 0, 0, 0); \
    acc[(MH)*4+2][3] = __builtin_amdgcn_mfma_f32_16x16x32_bf16(aq2, B3_, acc[(MH)*4+2][3], 0, 0, 0); \
    acc[(MH)*4+3][0] = __builtin_amdgcn_mfma_f32_16x16x32_bf16(aq3, B0_, acc[(MH)*4+3][0], 0, 0, 0); \
    acc[(MH)*4+3][1] = __builtin_amdgcn_mfma_f32_16x16x32_bf16(aq3, B1_, acc[(MH)*4+3][1], 0, 0, 0); \
    acc[(MH)*4+3][2] = __builtin_amdgcn_mfma_f32_16x16x32_bf16(aq3, B2_, acc[(MH)*4+3][2], 0, 0, 0); \
    acc[(MH)*4+3][3] = __builtin_amdgcn_mfma_f32_16x16x32_bf16(aq3, B3_, acc[(MH)*4+3][3], 0, 0, 0); \
    __builtin_amdgcn_s_setprio(0); } while (0)
#define BAR() __builtin_amdgcn_s_barrier()
#define VM4() asm volatile("s_waitcnt vmcnt(4)" ::: "memory")
#define VM0() asm volatile("s_waitcnt vmcnt(0)" ::: "memory")
#define SB()  __builtin_amdgcn_sched_barrier(0)

// Round t: compute tile t from CUR (A LDS) x BU (B regs); issue B(t+1)->BL and
// A(t+2)->STG; vmcnt(4) retires {A(t+1), B(t+1)}, keeps A(t+2); one barrier.
#define RND(CUR, STG, BU, BL, KTB, KTA) do { \
    BLOAD(BL, KTB); SB(); \
    GA4(STG, KTA);  SB(); \
    RA(CUR, 0, 0); MF16(0, BU##0, BU##1, BU##2, BU##3); \
    RA(CUR, 0, 1); MF16(1, BU##0, BU##1, BU##2, BU##3); \
    RA(CUR, 1, 0); MF16(0, BU##4, BU##5, BU##6, BU##7); \
    RA(CUR, 1, 1); MF16(1, BU##4, BU##5, BU##6, BU##7); \
    VM4(); BAR(); } while (0)

    // Prologue: A(0)->b0, B(0)->bp, A(1)->b1; retire A(0)+B(0), keep A(1).
    GA4(b0, 0);
    BLOAD(bp, 0); SB();
    GA4(b1, 1);   SB();
    VM4(); BAR();

    // Rounds 0..11 (buffer period 3 x B-set period 2 = 6)
    #pragma unroll 1
    for (int t6 = 0; t6 < 12; t6 += 6) {
        RND(b0, b2, bp, bq, t6 + 1, t6 + 2);
        RND(b1, b0, bq, bp, t6 + 2, t6 + 3);
        RND(b2, b1, bp, bq, t6 + 3, t6 + 4);
        RND(b0, b2, bq, bp, t6 + 4, t6 + 5);
        RND(b1, b0, bp, bq, t6 + 5, t6 + 6);
        RND(b2, b1, bq, bp, t6 + 6, t6 + 7);
    }
    // Rounds 12, 13
    RND(b0, b2, bp, bq, 13, 14);
    RND(b1, b0, bq, bp, 14, 15);
    // Round 14 (tile14 in b2, bp): load B(15) only; full drain (last staging).
    BLOAD(bq, 15); SB();
    RA(b2, 0, 0); MF16(0, bp0, bp1, bp2, bp3);
    RA(b2, 0, 1); MF16(1, bp0, bp1, bp2, bp3);
    RA(b2, 1, 0); MF16(0, bp4, bp5, bp6, bp7);
    RA(b2, 1, 1); MF16(1, bp4, bp5, bp6, bp7);
    VM0(); BAR();
    // Round 15 (tile15 in b0, bq): pure compute.
    RA(b0, 0, 0); MF16(0, bq0, bq1, bq2, bq3);
    RA(b0, 0, 1); MF16(1, bq0, bq1, bq2, bq3);
    RA(b0, 1, 0); MF16(0, bq4, bq5, bq6, bq7);
    RA(b0, 1, 1); MF16(1, bq4, bq5, bq6, bq7);

    // Epilogue: bias + cyclic activation; selector = col%4 = lane&3 (branchless).
    // Normal stores (L2 merges 64B wave segments; WRITE = 262MB proven).
    const int s = lane & 3;
    const float kmul = (s == 0) ? -2.f : -1.f;
    const float aa   = (s == 0) ?  2.f :  1.f;
    const float cc   = (s == 0) ? -1.f :  0.f;
    const bool  is_sin  = (s == 1);
    const bool  is_relu = (s == 2);

    float bv[4];
    #pragma unroll
    for (int fn = 0; fn < 4; ++fn) bv[fn] = bias[n0 + w4 * 64 + fn * 16 + lrow];

    #pragma unroll
    for (int fm = 0; fm < 8; ++fm) {
        #pragma unroll
        for (int r = 0; r < 4; ++r) {
            const int gr = m0 + wr2 * 128 + fm * 16 + quad * 4 + r;
            float* op = O + (size_t)gr * OUT_F + n0 + w4 * 64 + lrow;
            #pragma unroll
            for (int fn = 0; fn < 4; ++fn) {
                const float y = acc[fm][fn][r] + bv[fn];
                const float e = __expf(kmul * y);
                const float g = fmaf(aa, __builtin_amdgcn_rcpf(1.f + e), cc);
                const float sv = __sinf(y);
                const float rv = fmaxf(y, 0.f);
                const float res = is_sin ? sv : (is_relu ? rv : g);
                op[fn * 16] = res;
            }
        }
    }
}

// ================= fallback (ws too small for Xb): reg-staged fused kernel ===========
__global__ __launch_bounds__(256)
void w_to_bf16(const float* __restrict__ W, __bf16* __restrict__ Wb) {
    const size_t i = ((size_t)blockIdx.x * 256 + threadIdx.x) * 16;
    f32x4 a0 = *(const f32x4*)(W + i);
    f32x4 a1 = *(const f32x4*)(W + i + 4);
    f32x4 a2 = *(const f32x4*)(W + i + 8);
    f32x4 a3 = *(const f32x4*)(W + i + 12);
    *(bf16x8*)(Wb + i)     = cvt8(a0, a1);
    *(bf16x8*)(Wb + i + 8) = cvt8(a2, a3);
}

__global__ __launch_bounds__(BDIM, 2)
void fused_fallback(const float* __restrict__ X, const __bf16* __restrict__ Wb,
                    const float* __restrict__ bias, float* __restrict__ O)
{
    __shared__ __attribute__((aligned(16))) unsigned char lds[3 * 32768];
    const int bx  = blockIdx.x;
    const int xcd = bx & 7;
    const int idx = bx >> 3;
    const int nt  = idx & 3;
    const int mt  = xcd + 8 * (idx >> 2);
    const int m0 = mt * BM;
    const int n0 = nt * BN;
    const int tid  = threadIdx.x;
    const int lane = tid & 63;
    const int wave = tid >> 6;
    const int wr2  = wave >> 2;
    const int w4   = wave & 3;
    const int lrow = lane & 15;
    const int quad = lane >> 4;

    // A reg-staged from f32 X (cvt in-kernel); B regs from Wb (L2).
    const int arow = tid >> 1;
    const int ah   = tid & 1;
    const float* asrc = X + (size_t)(m0 + arow) * IN_F + ah * 32;
    const int awr = ah * 16384 + (arow >> 4) * 1024 + (arow & 15) * 16;
    const __bf16* bgp = Wb + (size_t)(n0 + w4 * 64 + lrow) * IN_F + quad * 8;

    unsigned char* const b0 = lds;
    unsigned char* const b1 = lds + 32768;

    f32x4 acc[8][4];
    #pragma unroll
    for (int i = 0; i < 8; ++i)
        #pragma unroll
        for (int j = 0; j < 4; ++j)
            acc[i][j] = (f32x4){0.f, 0.f, 0.f, 0.f};
    f32x4 ar0, ar1, ar2, ar3, ar4, ar5, ar6, ar7;
    bf16x8 aq0, aq1, aq2, aq3;
    bf16x8 bp0, bp1, bp2, bp3, bp4, bp5, bp6, bp7;
    bf16x8 bq0, bq1, bq2, bq3, bq4, bq5, bq6, bq7;

#define ALOADF(KA) do { \
    ar0 = *(const f32x4*)(asrc + (KA));      ar1 = *(const f32x4*)(asrc + (KA) + 4);  \
    ar2 = *(const f32x4*)(asrc + (KA) + 8);  ar3 = *(const f32x4*)(asrc + (KA) + 12); \
    ar4 = *(const f32x4*)(asrc + (KA) + 16); ar5 = *(const f32x4*)(asrc + (KA) + 20); \
    ar6 = *(const f32x4*)(asrc + (KA) + 24); ar7 = *(const f32x4*)(asrc + (KA) + 28); } while (0)
#define DSWF(BUF) do { unsigned char* _w = (BUF) + awr; \
    *(bf16x8*)(_w)       = cvt8(ar0, ar1); \
    *(bf16x8*)(_w + 256) = cvt8(ar2, ar3); \
    *(bf16x8*)(_w + 512) = cvt8(ar4, ar5); \
    *(bf16x8*)(_w + 768) = cvt8(ar6, ar7); } while (0)
#define FRND(CUR, OPP, BU, BL, KTB, KTA) do { \
    BLOAD(BL, KTB); SB(); \
    DSWF(OPP); \
    if ((KTA) < 16 * 64) { ALOADF(KTA); SB(); } \
    RA(CUR, 0, 0); MF16(0, BU##0, BU##1, BU##2, BU##3); \
    RA(CUR, 0, 1); MF16(1, BU##0, BU##1, BU##2, BU##3); \
    RA(CUR, 1, 0); MF16(0, BU##4, BU##5, BU##6, BU##7); \
    RA(CUR, 1, 1); MF16(1, BU##4, BU##5, BU##6, BU##7); \
    asm volatile("s_waitcnt lgkmcnt(0)" ::: "memory"); BAR(); } while (0)

    ALOADF(0);
    BLOAD(bp, 0); SB();
    DSWF(b0);
    ALOADF(64);
    asm volatile("s_waitcnt lgkmcnt(0)" ::: "memory");
    BAR();

    #pragma unroll 1
    for (int t = 0; t < 14; t += 2) {
        FRND(b0, b1, bp, bq, t + 1, (t + 2) * 64);
        FRND(b1, b0, bq, bp, t + 2, (t + 3) * 64);
    }
    FRND(b0, b1, bp, bq, 15, 16 * 64);   // stages tile15 (regs), no more A loads
    // round 15: pure compute from b1 with bq
    RA(b1, 0, 0); MF16(0, bq0, bq1, bq2, bq3);
    RA(b1, 0, 1); MF16(1, bq0, bq1, bq2, bq3);
    RA(b1, 1, 0); MF16(0, bq4, bq5, bq6, bq7);
    RA(b1, 1, 1); MF16(1, bq4, bq5, bq6, bq7);

    const int s = lane & 3;
    const float kmul = (s == 0) ? -2.f : -1.f;
    const float aa   = (s == 0) ?  2.f :  1.f;
    const float cc   = (s == 0) ? -1.f :  0.f;
    const bool  is_sin  = (s == 1);
    const bool  is_relu = (s == 2);
    float bv[4];
    #pragma unroll
    for (int fn = 0; fn < 4; ++fn) bv[fn] = bias[n0 + w4 * 64 + fn * 16 + lrow];
    #pragma unroll
    for (int fm = 0; fm < 8; ++fm) {
        #pragma unroll
        for (int r = 0; r < 4; ++r) {
            const int gr = m0 + wr2 * 128 + fm * 16 + quad * 4 + r;
            float* op = O + (size_t)gr * OUT_F + n0 + w4 * 64 + lrow;
            #pragma unroll
            for (int fn = 0; fn < 4; ++fn) {
                const float y = acc[fm][fn][r] + bv[fn];
                const float e = __expf(kmul * y);
                const float gg = fmaf(aa, __builtin_amdgcn_rcpf(1.f + e), cc);
                const float sv = __sinf(y);
                const float rv = fmaxf(y, 0.f);
                const float res = is_sin ? sv : (is_relu ? rv : gg);
                op[fn * 16] = res;
            }
        }
    }
}

extern "C" void kernel_launch(void* const* d_in, const int* in_sizes, int n_in,
                              void* d_out, int out_size, void* d_ws, size_t ws_size,
                              hipStream_t stream) {
    const float* X = (const float*)d_in[0];
    const float* W = (const float*)d_in[1];
    const float* b = (const float*)d_in[2];
    float* O = (float*)d_out;

    const size_t nX = (size_t)B_ROWS * IN_F;
    const size_t nW = (size_t)OUT_F * IN_F;
    const int grid = (B_ROWS / BM) * (OUT_F / BN);  // 1024 blocks

    if (ws_size >= (nW + nX) * sizeof(__bf16)) {
        __bf16* Wb = (__bf16*)d_ws;
        __bf16* Xb = (__bf16*)d_ws + nW;
        cvt_all<<<2048 + 256, 256, 0, stream>>>(X, W, Xb, Wb);
        fused_linear_act<<<grid, BDIM, 0, stream>>>(Xb, Wb, b, O);
    } else {
        __bf16* Wb = (__bf16*)d_ws;   // 2 MB
        w_to_bf16<<<(int)(nW / (256 * 16)), 256, 0, stream>>>(W, Wb);
        fused_fallback<<<grid, BDIM, 0, stream>>>(X, Wb, b, O);
    }
}

// Round 12
// 580.357 us; speedup vs baseline: 1.1306x; 1.1306x over previous
//
#include <hip/hip_runtime.h>

// Problem constants (fixed by reference)
constexpr int B_ROWS = 65536;
constexpr int IN_F   = 1024;
constexpr int OUT_F  = 1024;

constexpr int BDIM = 512;            // 8 waves, 2M x 4N
constexpr int BM = 256, BN = 256, BK = 64;

typedef __bf16 bf16x8 __attribute__((ext_vector_type(8)));
typedef __bf16 bf16x4 __attribute__((ext_vector_type(4)));
typedef float  f32x4  __attribute__((ext_vector_type(4)));

__device__ __forceinline__ bf16x8 cvt8(f32x4 u0, f32x4 u1) {
    bf16x8 v;
    v[0] = (__bf16)u0[0]; v[1] = (__bf16)u0[1]; v[2] = (__bf16)u0[2]; v[3] = (__bf16)u0[3];
    v[4] = (__bf16)u1[0]; v[5] = (__bf16)u1[1]; v[6] = (__bf16)u1[2]; v[7] = (__bf16)u1[3];
    return v;
}

__device__ __forceinline__ bf16x4 cvt4(f32x4 a) {
    bf16x4 v;
    v[0] = (__bf16)a[0]; v[1] = (__bf16)a[1]; v[2] = (__bf16)a[2]; v[3] = (__bf16)a[3];
    return v;
}

// async global->LDS, 16B per lane (wave stages 1KB contiguous at uniform lds base)
__device__ __forceinline__ void glds16(const __bf16* g, unsigned char* l) {
    __builtin_amdgcn_global_load_lds(
        (const __attribute__((address_space(1))) unsigned int*)(const void*)g,
        (__attribute__((address_space(3))) unsigned int*)(void*)l,
        16, 0, 0);
}

// ---------------- f32 -> bf16 convert, fully-coalesced unit layout ------------------
// Lane l owns f32x4 unit (base + l): every load instr = 64 lanes x 16B = 1KB
// contiguous (100% line utilization; the old 4-sequential-dwordx4-per-thread
// pattern touched 64 distinct lines PER INSTR at 25% utilization -> 4x request
// pressure, 4.5 TB/s). Stores 8B/lane = 512B/instr contiguous. nt loads (X dead
// after read, don't evict Xb/Wb from L3); cached stores (Xb must stay L3-hot).
__global__ __launch_bounds__(256)
void cvt_all(const float* __restrict__ X, const float* __restrict__ W,
             __bf16* __restrict__ Xb, __bf16* __restrict__ Wb) {
    const int b = blockIdx.x;
    const int t = threadIdx.x;
    if (b < 4096) {   // X: 16.78M f32x4 units, 16/thread, grid-stride 1M units
        size_t u = (size_t)b * 256 + t;
        const f32x4* __restrict__ xi = (const f32x4*)X;
        #pragma unroll 4
        for (int it = 0; it < 16; ++it, u += (size_t)4096 * 256) {
            f32x4 a = __builtin_nontemporal_load(xi + u);
            *(bf16x4*)(Xb + u * 4) = cvt4(a);
        }
    } else {          // W: 262144 units, 4/thread
        size_t u = (size_t)(b - 4096) * 256 + t;
        const f32x4* __restrict__ wi = (const f32x4*)W;
        #pragma unroll 4
        for (int it = 0; it < 4; ++it, u += (size_t)256 * 256) {
            f32x4 a = __builtin_nontemporal_load(wi + u);
            *(bf16x4*)(Wb + u * 4) = cvt4(a);
        }
    }
}

// ---------------- 256x256, BK=64, 8-wave, 4-phase/K-tile GEMM (round-4/10 proven) ----
// Grid 1024, one tile per block. Measured 195-216us across sessions, MfmaUtil
// 27-30%, WRITE 262MB, FETCH 98MB, 0 bank conflicts. LDS buffer (64KB): A kh0/kh1
// [0,32K), B [32K,64K), MFMA-order 1KB blocks (lane l: row 16bi+(l&15), k-seg
// (l>>4)*8, byte l*16). Wave w stages blocks {2w,2w+1}/quadrant via 2 glds16.
// Per phase: glds issue, ds_reads, BAR, 16 MFMA (setprio), BAR. End-of-round
// vmcnt(4) retires tile t+1 fully, keeps tile t+2's kh0 in flight.
// Structural notes from failed experiments (do not revisit):
//  - r8/r9: chaining M-tiles per block => unexplained 3x WRITE amplification.
//  - r11: B direct-to-registers (1 barrier/round) => 257us (worse than 216).
//  - r5/r6/r7: fusing X f32->bf16 into the GEMM (reg- or LDS-staged) => 285-330.
__global__ __launch_bounds__(BDIM, 2)
void fused_linear_act(const __bf16* __restrict__ Xb,  // [B_ROWS][IN_F] bf16
                      const __bf16* __restrict__ Wb,  // [OUT_F][IN_F] bf16
                      const float* __restrict__ bias, // [OUT_F]
                      float* __restrict__ O)          // [B_ROWS][OUT_F]
{
    __shared__ __attribute__((aligned(16))) unsigned char lds[2 * 65536];  // 128 KB

    const int bx  = blockIdx.x;                 // 1024 blocks
    // XCD-aware: 4 consecutive blocks per XCD share one A panel (L2 reuse).
    const int xcd = bx & 7;
    const int idx = bx >> 3;
    const int nt  = idx & 3;
    const int mt  = xcd + 8 * (idx >> 2);
    const int m0 = mt * BM;
    const int n0 = nt * BN;

    const int tid  = threadIdx.x;
    const int lane = tid & 63;
    const int wave = tid >> 6;                  // 0..7, 2M x 4N
    const int wr2  = wave >> 2;
    const int w4   = wave & 3;
    const int lrow = lane & 15;
    const int quad = lane >> 4;

    // staging global sources (per-lane, MFMA-order pre-swizzle)
    const __bf16* agp = Xb + (size_t)(m0 + 32 * wave + lrow) * IN_F + quad * 8;
    const __bf16* bgp = Wb + (size_t)(n0 + 32 * wave + lrow) * IN_F + quad * 8;

    unsigned char* const b0 = lds;
    unsigned char* const b1 = lds + 65536;

    f32x4 acc[8][4];
    #pragma unroll
    for (int i = 0; i < 8; ++i)
        #pragma unroll
        for (int j = 0; j < 4; ++j)
            acc[i][j] = (f32x4){0.f, 0.f, 0.f, 0.f};

    bf16x8 aq0, aq1, aq2, aq3, bq0, bq1, bq2, bq3;

#define GA(BUF, KH, K) do { unsigned char* _d = (BUF) + (KH) * 16384 + wave * 2048; \
    glds16(agp + (K), _d); glds16(agp + (K) + 16 * IN_F, _d + 1024); } while (0)
#define GB(BUF, KH, K) do { unsigned char* _d = (BUF) + 32768 + (KH) * 16384 + wave * 2048; \
    glds16(bgp + (K), _d); glds16(bgp + (K) + 16 * IN_F, _d + 1024); } while (0)
#define RA(BUF, KH, MH) do { \
    const unsigned char* _r = (BUF) + (KH) * 16384 + (wr2 * 8 + (MH) * 4) * 1024 + lane * 16; \
    aq0 = *(const bf16x8*)(_r);        aq1 = *(const bf16x8*)(_r + 1024); \
    aq2 = *(const bf16x8*)(_r + 2048); aq3 = *(const bf16x8*)(_r + 3072); } while (0)
#define RB(BUF, KH) do { \
    const unsigned char* _r = (BUF) + 32768 + (KH) * 16384 + (w4 * 4) * 1024 + lane * 16; \
    bq0 = *(const bf16x8*)(_r);        bq1 = *(const bf16x8*)(_r + 1024); \
    bq2 = *(const bf16x8*)(_r + 2048); bq3 = *(const bf16x8*)(_r + 3072); } while (0)
#define MFMA1(MH, I, J) acc[(MH)*4+(I)][(J)] = \
    __builtin_amdgcn_mfma_f32_16x16x32_bf16(aq##I, bq##J, acc[(MH)*4+(I)][(J)], 0, 0, 0)
#define MFMAQ(MH) do { __builtin_amdgcn_s_setprio(1); \
    MFMA1(MH,0,0); MFMA1(MH,0,1); MFMA1(MH,0,2); MFMA1(MH,0,3); \
    MFMA1(MH,1,0); MFMA1(MH,1,1); MFMA1(MH,1,2); MFMA1(MH,1,3); \
    MFMA1(MH,2,0); MFMA1(MH,2,1); MFMA1(MH,2,2); MFMA1(MH,2,3); \
    MFMA1(MH,3,0); MFMA1(MH,3,1); MFMA1(MH,3,2); MFMA1(MH,3,3); \
    __builtin_amdgcn_s_setprio(0); } while (0)
#define BAR() __builtin_amdgcn_s_barrier()
#define VM4() asm volatile("s_waitcnt vmcnt(4)" ::: "memory")
#define VM0() asm volatile("s_waitcnt vmcnt(0)" ::: "memory")

// Steady round KT (tile KT in CUR): stage (KT+1)-kh1 -> OPP, (KT+2)-kh0 -> CUR.
#define SROUND(CUR, OPP, KT) do { \
    GA(OPP, 1, ((KT) + 1) * 64 + 32); RB(CUR, 0); RA(CUR, 0, 0); \
             BAR(); MFMAQ(0); BAR(); \
    GB(OPP, 1, ((KT) + 1) * 64 + 32); RA(CUR, 0, 1); \
             BAR(); MFMAQ(1); BAR(); \
    GA(CUR, 0, ((KT) + 2) * 64); RB(CUR, 1); RA(CUR, 1, 0); \
             BAR(); MFMAQ(0); BAR(); \
    GB(CUR, 0, ((KT) + 2) * 64); RA(CUR, 1, 1); \
             BAR(); MFMAQ(1); VM4(); BAR(); \
} while (0)

    // Prologue: tile0 fully staged into b0; tile1 kh0 into b1; retire tile0 only.
    GA(b0, 0, 0);  GB(b0, 0, 0);
    GA(b0, 1, 32); GB(b0, 1, 32);
    GA(b1, 0, 64); GB(b1, 0, 64);
    VM4();          // tile0's 8 retired; tile1-kh0's 4 stay in flight
    BAR();

    #pragma unroll 1
    for (int kt = 0; kt < 14; kt += 2) {
        SROUND(b0, b1, kt);
        SROUND(b1, b0, kt + 1);
    }
    // Round 14 (tile14 in b0): stage tile15 kh1; no tile16 -> drain at end.
    GA(b1, 1, 15 * 64 + 32); RB(b0, 0); RA(b0, 0, 0); BAR(); MFMAQ(0); BAR();
    GB(b1, 1, 15 * 64 + 32); RA(b0, 0, 1);            BAR(); MFMAQ(1); BAR();
    RB(b0, 1); RA(b0, 1, 0);                          BAR(); MFMAQ(0); BAR();
    RA(b0, 1, 1);                                     BAR(); MFMAQ(1); VM0(); BAR();
    // Round 15 (tile15 in b1): pure compute.
    RB(b1, 0); RA(b1, 0, 0); BAR(); MFMAQ(0); BAR();
    RA(b1, 0, 1);            BAR(); MFMAQ(1); BAR();
    RB(b1, 1); RA(b1, 1, 0); BAR(); MFMAQ(0); BAR();
    RA(b1, 1, 1);            BAR(); MFMAQ(1);

    // Epilogue: bias + cyclic activation; selector = col%4 = lane&3 (branchless).
    // Normal stores — L2 merges the 64B wave segments (WRITE = 262MB proven).
    const int s = lane & 3;
    const float kmul = (s == 0) ? -2.f : -1.f;
    const float aa   = (s == 0) ?  2.f :  1.f;
    const float cc   = (s == 0) ? -1.f :  0.f;
    const bool  is_sin  = (s == 1);
    const bool  is_relu = (s == 2);

    float bv[4];
    #pragma unroll
    for (int fn = 0; fn < 4; ++fn) bv[fn] = bias[n0 + w4 * 64 + fn * 16 + lrow];

    #pragma unroll
    for (int fm = 0; fm < 8; ++fm) {
        #pragma unroll
        for (int r = 0; r < 4; ++r) {
            const int gr = m0 + wr2 * 128 + fm * 16 + quad * 4 + r;
            float* op = O + (size_t)gr * OUT_F + n0 + w4 * 64 + lrow;
            #pragma unroll
            for (int fn = 0; fn < 4; ++fn) {
                const float y = acc[fm][fn][r] + bv[fn];
                const float e = __expf(kmul * y);
                const float g = fmaf(aa, __builtin_amdgcn_rcpf(1.f + e), cc);
                const float sv = __sinf(y);
                const float rv = fmaxf(y, 0.f);
                const float res = is_sin ? sv : (is_relu ? rv : g);
                op[fn * 16] = res;
            }
        }
    }
}

// ================= fallback (ws too small for Xb): reg-staged fused kernel ===========
__global__ __launch_bounds__(256)
void w_to_bf16(const float* __restrict__ W, __bf16* __restrict__ Wb) {
    const size_t i = ((size_t)blockIdx.x * 256 + threadIdx.x) * 16;
    f32x4 a0 = *(const f32x4*)(W + i);
    f32x4 a1 = *(const f32x4*)(W + i + 4);
    f32x4 a2 = *(const f32x4*)(W + i + 8);
    f32x4 a3 = *(const f32x4*)(W + i + 12);
    *(bf16x8*)(Wb + i)     = cvt8(a0, a1);
    *(bf16x8*)(Wb + i + 8) = cvt8(a2, a3);
}

__global__ __launch_bounds__(BDIM, 2)
void fused_fallback(const float* __restrict__ X, const __bf16* __restrict__ Wb,
                    const float* __restrict__ bias, float* __restrict__ O)
{
    __shared__ __attribute__((aligned(16))) unsigned char lds[2 * 65536];
    const int bx  = blockIdx.x;
    const int xcd = bx & 7;
    const int idx = bx >> 3;
    const int nt  = idx & 3;
    const int mt  = xcd + 8 * (idx >> 2);
    const int m0 = mt * BM;
    const int n0 = nt * BN;
    const int tid  = threadIdx.x;
    const int lane = tid & 63;
    const int wave = tid >> 6;
    const int wr2  = wave >> 2;
    const int w4   = wave & 3;
    const int lrow = lane & 15;
    const int quad = lane >> 4;
    const int arow = tid >> 1;
    const int ah   = tid & 1;
    const float* asrc = X + (size_t)(m0 + arow) * IN_F + ah * 32;
    const int awr = ah * 16384 + (arow >> 4) * 1024 + (arow & 15) * 16;
    const __bf16* bgp = Wb + (size_t)(n0 + 32 * wave + lrow) * IN_F + quad * 8;
    unsigned char* const b0 = lds;
    unsigned char* const b1 = lds + 65536;
    f32x4 acc[8][4];
    #pragma unroll
    for (int i = 0; i < 8; ++i)
        #pragma unroll
        for (int j = 0; j < 4; ++j)
            acc[i][j] = (f32x4){0.f, 0.f, 0.f, 0.f};
    f32x4 ar0, ar1, ar2, ar3, ar4, ar5, ar6, ar7;
    bf16x8 aq0, aq1, aq2, aq3, bq0, bq1, bq2, bq3;
#define ALOAD(KA) do { \
    ar0 = *(const f32x4*)(asrc + (KA));      ar1 = *(const f32x4*)(asrc + (KA) + 4);  \
    ar2 = *(const f32x4*)(asrc + (KA) + 8);  ar3 = *(const f32x4*)(asrc + (KA) + 12); \
    ar4 = *(const f32x4*)(asrc + (KA) + 16); ar5 = *(const f32x4*)(asrc + (KA) + 20); \
    ar6 = *(const f32x4*)(asrc + (KA) + 24); ar7 = *(const f32x4*)(asrc + (KA) + 28); } while (0)
#define DSW(BUF) do { unsigned char* _w = (BUF) + awr; \
    *(bf16x8*)(_w)       = cvt8(ar0, ar1); \
    *(bf16x8*)(_w + 256) = cvt8(ar2, ar3); \
    *(bf16x8*)(_w + 512) = cvt8(ar4, ar5); \
    *(bf16x8*)(_w + 768) = cvt8(ar6, ar7); } while (0)
#define GBALL(BUF, K) do { unsigned char* _d0 = (BUF) + 32768 + wave * 2048; \
    unsigned char* _d1 = _d0 + 16384; \
    glds16(bgp + (K), _d0);      glds16(bgp + (K) + 16 * IN_F, _d0 + 1024); \
    glds16(bgp + (K) + 32, _d1); glds16(bgp + (K) + 32 + 16 * IN_F, _d1 + 1024); } while (0)
#define FROUND(CUR, OPP, DO_STAGE, KB1, DO_ALOAD, KA2, VMW) do { \
    if (DO_STAGE) { GBALL(OPP, KB1); DSW(OPP); } \
    if (DO_ALOAD) { ALOAD(KA2); __builtin_amdgcn_sched_barrier(0); } \
    RB(CUR, 0); RA(CUR, 0, 0); BAR(); MFMAQ(0); BAR(); \
    RA(CUR, 0, 1); BAR(); MFMAQ(1); BAR(); \
    RB(CUR, 1); RA(CUR, 1, 0); BAR(); MFMAQ(0); BAR(); \
    RA(CUR, 1, 1); BAR(); MFMAQ(1); VMW; BAR(); \
} while (0)
    ALOAD(0);
    GBALL(b0, 0);
    DSW(b0);
    ALOAD(64);
    asm volatile("s_waitcnt vmcnt(8) lgkmcnt(0)" ::: "memory");
    BAR();
    #pragma unroll 1
    for (int t = 0; t < 14; t += 2) {
        FROUND(b0, b1, true, (t + 1) * 64, true, (t + 2) * 64, asm volatile("s_waitcnt vmcnt(8)" ::: "memory"));
        FROUND(b1, b0, true, (t + 2) * 64, true, (t + 3) * 64, asm volatile("s_waitcnt vmcnt(8)" ::: "memory"));
    }
    FROUND(b0, b1, true, 15 * 64, false, 0, VM0());
    FROUND(b1, b0, false, 0, false, 0, (void)0);
    const int s = lane & 3;
    const float kmul = (s == 0) ? -2.f : -1.f;
    const float aa   = (s == 0) ?  2.f :  1.f;
    const float cc   = (s == 0) ? -1.f :  0.f;
    const bool  is_sin  = (s == 1);
    const bool  is_relu = (s == 2);
    float bv[4];
    #pragma unroll
    for (int fn = 0; fn < 4; ++fn) bv[fn] = bias[n0 + w4 * 64 + fn * 16 + lrow];
    #pragma unroll
    for (int fm = 0; fm < 8; ++fm) {
        #pragma unroll
        for (int r = 0; r < 4; ++r) {
            const int gr = m0 + wr2 * 128 + fm * 16 + quad * 4 + r;
            float* op = O + (size_t)gr * OUT_F + n0 + w4 * 64 + lrow;
            #pragma unroll
            for (int fn = 0; fn < 4; ++fn) {
                const float y = acc[fm][fn][r] + bv[fn];
                const float e = __expf(kmul * y);
                const float gg = fmaf(aa, __builtin_amdgcn_rcpf(1.f + e), cc);
                const float sv = __sinf(y);
                const float rv = fmaxf(y, 0.f);
                const float res = is_sin ? sv : (is_relu ? rv : gg);
                op[fn * 16] = res;
            }
        }
    }
}

extern "C" void kernel_launch(void* const* d_in, const int* in_sizes, int n_in,
                              void* d_out, int out_size, void* d_ws, size_t ws_size,
                              hipStream_t stream) {
    const float* X = (const float*)d_in[0];
    const float* W = (const float*)d_in[1];
    const float* b = (const float*)d_in[2];
    float* O = (float*)d_out;

    const size_t nX = (size_t)B_ROWS * IN_F;
    const size_t nW = (size_t)OUT_F * IN_F;
    const int grid = (B_ROWS / BM) * (OUT_F / BN);  // 1024 blocks

    if (ws_size >= (nW + nX) * sizeof(__bf16)) {
        __bf16* Wb = (__bf16*)d_ws;
        __bf16* Xb = (__bf16*)d_ws + nW;
        cvt_all<<<4096 + 256, 256, 0, stream>>>(X, W, Xb, Wb);
        fused_linear_act<<<grid, BDIM, 0, stream>>>(Xb, Wb, b, O);
    } else {
        __bf16* Wb = (__bf16*)d_ws;   // 2 MB
        w_to_bf16<<<(int)(nW / (256 * 16)), 256, 0, stream>>>(W, Wb);
        fused_fallback<<<grid, BDIM, 0, stream>>>(X, Wb, b, O);
    }
}